// Round 15
// baseline (643.098 us; speedup 1.0000x reference)
//
#include <hip/hip_runtime.h>
#include <hip/hip_bf16.h>

typedef unsigned short u16;
typedef unsigned int u32;
typedef __attribute__((ext_vector_type(8))) short short8;
typedef __attribute__((ext_vector_type(4))) float floatx4;

#define N_PTS 16384
#define N_GRID 4096
#define GPTS 512
#define HD 128
#define DEG 16
#define QB 8
#define EB 128

__device__ __forceinline__ float silu_f(float x) { return x / (1.0f + __expf(-x)); }
__device__ __forceinline__ short f2bf(float x) { return (short)__bfloat16_as_ushort(__float2bfloat16(x)); }

__global__ void k_fillf(float* out, float v, int n) {
    int i = blockIdx.x * blockDim.x + threadIdx.x;
    if (i < n) out[i] = v;
}

__global__ void k_init(const float* __restrict__ qp, const float* __restrict__ codes,
                       float* __restrict__ x_q, float* __restrict__ h_g, float* __restrict__ h_q,
                       float* __restrict__ Bq) {
    int stride = gridDim.x * blockDim.x;
    int i0 = blockIdx.x * blockDim.x + threadIdx.x;
    for (int i = i0; i < N_PTS * 3; i += stride) x_q[i] = qp[i];
    for (int i = i0; i < N_GRID * HD; i += stride) h_g[i] = codes[i];
    for (int i = i0; i < N_PTS * HD; i += stride) { h_q[i] = 0.0f; Bq[i] = 0.0f; }
}

// transpose We2 -> bf16 wsT[layer][f*128+k]
__global__ void k_prep(const float* __restrict__ eW2, short* __restrict__ wsT) {
    int idx = blockIdx.x * blockDim.x + threadIdx.x;
    if (idx >= 4 * HD * HD) return;
    int l = idx >> 14, rem = idx & 16383, f = rem >> 7, k = rem & 127;
    wsT[idx] = f2bf(eW2[l * 16384 + k * HD + f]);
}

// ---------------- grid nodes only: A_g + h_g update ----------------
__global__ __launch_bounds__(256) void k_ga(
    const float* __restrict__ hg, float* __restrict__ Ag,
    const float* __restrict__ W1top, const float* __restrict__ b1,
    const float* __restrict__ Wn1top, const float* __restrict__ bn1,
    const float* __restrict__ Wn2, const float* __restrict__ bn2,
    int updateH, float* __restrict__ hg_out) {
    __shared__ float T1[HD * 36];
    __shared__ float T2[HD * 36];
    int tid = threadIdx.x;
    int n0 = blockIdx.x * 32;
    int f0 = (tid & 31) * 4;
    int ng = (tid >> 5) * 4;
    {
        int q = tid & 31, j0 = (tid >> 5) * 16;
#pragma unroll
        for (int s = 0; s < 4; s++) {
            float4 v = *(const float4*)&hg[(n0 + q) * HD + j0 + s * 4];
            T1[(j0 + s * 4 + 0) * 36 + q] = v.x;
            T1[(j0 + s * 4 + 1) * 36 + q] = v.y;
            T1[(j0 + s * 4 + 2) * 36 + q] = v.z;
            T1[(j0 + s * 4 + 3) * 36 + q] = v.w;
        }
    }
    __syncthreads();
    float4 acc[4];
    {
        float4 bv = *(const float4*)&b1[f0];
#pragma unroll
        for (int qq = 0; qq < 4; qq++) acc[qq] = bv;
#pragma unroll 4
        for (int j = 0; j < HD; j++) {
            float4 a = *(const float4*)&T1[j * 36 + ng];
            float4 w = *(const float4*)&W1top[j * HD + f0];
            acc[0].x += a.x * w.x; acc[0].y += a.x * w.y; acc[0].z += a.x * w.z; acc[0].w += a.x * w.w;
            acc[1].x += a.y * w.x; acc[1].y += a.y * w.y; acc[1].z += a.y * w.z; acc[1].w += a.y * w.w;
            acc[2].x += a.z * w.x; acc[2].y += a.z * w.y; acc[2].z += a.z * w.z; acc[2].w += a.z * w.w;
            acc[3].x += a.w * w.x; acc[3].y += a.w * w.y; acc[3].z += a.w * w.z; acc[3].w += a.w * w.w;
        }
#pragma unroll
        for (int qq = 0; qq < 4; qq++)
            *(float4*)&Ag[(n0 + ng + qq) * HD + f0] = acc[qq];
    }
    if (updateH) {
        float4 bv = *(const float4*)&bn1[f0];
#pragma unroll
        for (int qq = 0; qq < 4; qq++) acc[qq] = bv;
#pragma unroll 4
        for (int j = 0; j < HD; j++) {
            float4 a = *(const float4*)&T1[j * 36 + ng];
            float4 w = *(const float4*)&Wn1top[j * HD + f0];
            acc[0].x += a.x * w.x; acc[0].y += a.x * w.y; acc[0].z += a.x * w.z; acc[0].w += a.x * w.w;
            acc[1].x += a.y * w.x; acc[1].y += a.y * w.y; acc[1].z += a.y * w.z; acc[1].w += a.y * w.w;
            acc[2].x += a.z * w.x; acc[2].y += a.z * w.y; acc[2].z += a.z * w.z; acc[2].w += a.z * w.w;
            acc[3].x += a.w * w.x; acc[3].y += a.w * w.y; acc[3].z += a.w * w.z; acc[3].w += a.w * w.w;
        }
#pragma unroll
        for (int qq = 0; qq < 4; qq++) {
            T2[(f0 + 0) * 36 + ng + qq] = silu_f(acc[qq].x);
            T2[(f0 + 1) * 36 + ng + qq] = silu_f(acc[qq].y);
            T2[(f0 + 2) * 36 + ng + qq] = silu_f(acc[qq].z);
            T2[(f0 + 3) * 36 + ng + qq] = silu_f(acc[qq].w);
        }
        __syncthreads();
        bv = *(const float4*)&bn2[f0];
#pragma unroll
        for (int qq = 0; qq < 4; qq++) acc[qq] = bv;
#pragma unroll 4
        for (int j = 0; j < HD; j++) {
            float4 a = *(const float4*)&T2[j * 36 + ng];
            float4 w = *(const float4*)&Wn2[j * HD + f0];
            acc[0].x += a.x * w.x; acc[0].y += a.x * w.y; acc[0].z += a.x * w.z; acc[0].w += a.x * w.w;
            acc[1].x += a.y * w.x; acc[1].y += a.y * w.y; acc[1].z += a.y * w.z; acc[1].w += a.y * w.w;
            acc[2].x += a.z * w.x; acc[2].y += a.z * w.y; acc[2].z += a.z * w.z; acc[2].w += a.z * w.w;
            acc[3].x += a.w * w.x; acc[3].y += a.w * w.y; acc[3].z += a.w * w.z; acc[3].w += a.w * w.w;
        }
#pragma unroll
        for (int qq = 0; qq < 4; qq++) {
            float4 h;
            h.x = T1[(f0 + 0) * 36 + ng + qq] + acc[qq].x;
            h.y = T1[(f0 + 1) * 36 + ng + qq] + acc[qq].y;
            h.z = T1[(f0 + 2) * 36 + ng + qq] + acc[qq].z;
            h.w = T1[(f0 + 3) * 36 + ng + qq] + acc[qq].w;
            *(float4*)&hg_out[(n0 + ng + qq) * HD + f0] = h;
        }
    }
}

// ---------------- fused node MLP + Bq: h += MLP(h,mg); Bq = h_new @ W1mid ----------------
__global__ __launch_bounds__(256) void k_nb(
    float* __restrict__ hq, const float* __restrict__ mg,
    const float* __restrict__ Wn1, const float* __restrict__ bn1,
    const float* __restrict__ Wn2, const float* __restrict__ bn2,
    const float* __restrict__ W1mid, float* __restrict__ Bq) {
    __shared__ float aT[256 * 36];
    __shared__ float stT[HD * 36];
    int tid = threadIdx.x;
    int q0 = blockIdx.x * 32;
    {
        int q = tid & 31, j0 = (tid >> 5) * 16;
#pragma unroll
        for (int s = 0; s < 4; s++) {
            float4 v = *(const float4*)&hq[(q0 + q) * HD + j0 + s * 4];
            aT[(j0 + s * 4 + 0) * 36 + q] = v.x;
            aT[(j0 + s * 4 + 1) * 36 + q] = v.y;
            aT[(j0 + s * 4 + 2) * 36 + q] = v.z;
            aT[(j0 + s * 4 + 3) * 36 + q] = v.w;
            float4 m = *(const float4*)&mg[(q0 + q) * HD + j0 + s * 4];
            aT[(128 + j0 + s * 4 + 0) * 36 + q] = m.x;
            aT[(128 + j0 + s * 4 + 1) * 36 + q] = m.y;
            aT[(128 + j0 + s * 4 + 2) * 36 + q] = m.z;
            aT[(128 + j0 + s * 4 + 3) * 36 + q] = m.w;
        }
    }
    __syncthreads();
    int f0 = (tid & 31) * 4;
    int qg = (tid >> 5) * 4;
    float4 bn1v = *(const float4*)&bn1[f0];
    float4 acc[4];
#pragma unroll
    for (int qq = 0; qq < 4; qq++) acc[qq] = bn1v;
#pragma unroll 4
    for (int j = 0; j < 256; j++) {
        float4 a = *(const float4*)&aT[j * 36 + qg];
        float4 w = *(const float4*)&Wn1[j * HD + f0];
        acc[0].x += a.x * w.x; acc[0].y += a.x * w.y; acc[0].z += a.x * w.z; acc[0].w += a.x * w.w;
        acc[1].x += a.y * w.x; acc[1].y += a.y * w.y; acc[1].z += a.y * w.z; acc[1].w += a.y * w.w;
        acc[2].x += a.z * w.x; acc[2].y += a.z * w.y; acc[2].z += a.z * w.z; acc[2].w += a.z * w.w;
        acc[3].x += a.w * w.x; acc[3].y += a.w * w.y; acc[3].z += a.w * w.z; acc[3].w += a.w * w.w;
    }
#pragma unroll
    for (int qq = 0; qq < 4; qq++) {
        stT[(f0 + 0) * 36 + qg + qq] = silu_f(acc[qq].x);
        stT[(f0 + 1) * 36 + qg + qq] = silu_f(acc[qq].y);
        stT[(f0 + 2) * 36 + qg + qq] = silu_f(acc[qq].z);
        stT[(f0 + 3) * 36 + qg + qq] = silu_f(acc[qq].w);
    }
    __syncthreads();
    float4 bn2v = *(const float4*)&bn2[f0];
#pragma unroll
    for (int qq = 0; qq < 4; qq++) acc[qq] = bn2v;
#pragma unroll 4
    for (int j = 0; j < HD; j++) {
        float4 a = *(const float4*)&stT[j * 36 + qg];
        float4 w = *(const float4*)&Wn2[j * HD + f0];
        acc[0].x += a.x * w.x; acc[0].y += a.x * w.y; acc[0].z += a.x * w.z; acc[0].w += a.x * w.w;
        acc[1].x += a.y * w.x; acc[1].y += a.y * w.y; acc[1].z += a.y * w.z; acc[1].w += a.y * w.w;
        acc[2].x += a.z * w.x; acc[2].y += a.z * w.y; acc[2].z += a.z * w.z; acc[2].w += a.z * w.w;
        acc[3].x += a.w * w.x; acc[3].y += a.w * w.y; acc[3].z += a.w * w.z; acc[3].w += a.w * w.w;
    }
    // h_new = h + o: write global + update aT in place (rows 0..127 only read in GEMM1, done)
#pragma unroll
    for (int qq = 0; qq < 4; qq++) {
        float4 h;
        h.x = aT[(f0 + 0) * 36 + qg + qq] + acc[qq].x;
        h.y = aT[(f0 + 1) * 36 + qg + qq] + acc[qq].y;
        h.z = aT[(f0 + 2) * 36 + qg + qq] + acc[qq].z;
        h.w = aT[(f0 + 3) * 36 + qg + qq] + acc[qq].w;
        *(float4*)&hq[(q0 + qg + qq) * HD + f0] = h;
        aT[(f0 + 0) * 36 + qg + qq] = h.x;
        aT[(f0 + 1) * 36 + qg + qq] = h.y;
        aT[(f0 + 2) * 36 + qg + qq] = h.z;
        aT[(f0 + 3) * 36 + qg + qq] = h.w;
    }
    __syncthreads();
    // Bq = h_new @ W1mid
    float4 acc2[4] = {};
#pragma unroll 4
    for (int j = 0; j < HD; j++) {
        float4 a = *(const float4*)&aT[j * 36 + qg];
        float4 w = *(const float4*)&W1mid[j * HD + f0];
        acc2[0].x += a.x * w.x; acc2[0].y += a.x * w.y; acc2[0].z += a.x * w.z; acc2[0].w += a.x * w.w;
        acc2[1].x += a.y * w.x; acc2[1].y += a.y * w.y; acc2[1].z += a.y * w.z; acc2[1].w += a.y * w.w;
        acc2[2].x += a.z * w.x; acc2[2].y += a.z * w.y; acc2[2].z += a.z * w.z; acc2[2].w += a.z * w.w;
        acc2[3].x += a.w * w.x; acc2[3].y += a.w * w.y; acc2[3].z += a.w * w.z; acc2[3].w += a.w * w.w;
    }
#pragma unroll
    for (int qq = 0; qq < 4; qq++)
        *(float4*)&Bq[(q0 + qg + qq) * HD + f0] = acc2[qq];
}

// ---------------- MFMA edge kernel: 8 q/block, 2 q/wave, n-split two-pass (32 AGPR) ----------------
template <int OUTT, bool FIN>
__global__ __launch_bounds__(256, 4) void k_edge(
    const float* __restrict__ Ag, const float* __restrict__ Bq, float* __restrict__ x_q,
    const float* __restrict__ wdrow, const short* __restrict__ wsT,
    const float* __restrict__ b2v, const float* __restrict__ Wc, const float* __restrict__ cbp,
    const int* __restrict__ erow, const float* __restrict__ gridp,
    const float* __restrict__ qp, float* __restrict__ out, float* __restrict__ maggr) {
    __shared__ float sdist[EB];
    __shared__ float scm[EB];
    __shared__ float sdir[3 * EB];
    __shared__ int   sgi[EB];
    __shared__ float scoef[EB * OUTT];
    __shared__ float xs[QB * 3];

    int tid = threadIdx.x;
    int q0 = blockIdx.x * QB;
    int wid = tid >> 6, lane = tid & 63, quad = lane >> 4, c = lane & 15;

    if (tid < QB * 3) xs[tid] = x_q[q0 * 3 + tid];
    __syncthreads();
    if (tid < EB) {
        int e = tid, q = e >> 4;
        int gi = erow[q0 * DEG + e] - N_PTS;
        sgi[e] = gi;
        int gl = gi & (GPTS - 1);
        float r0 = gridp[gl * 3 + 0] - xs[q * 3 + 0];
        float r1 = gridp[gl * 3 + 1] - xs[q * 3 + 1];
        float r2 = gridp[gl * 3 + 2] - xs[q * 3 + 2];
        float dist = sqrtf(r0 * r0 + r1 * r1 + r2 * r2);
        float inv = 1.0f / (dist + 1e-8f);
        sdist[e] = dist;
        sdir[0 * EB + e] = r0 * inv;
        sdir[1 * EB + e] = r1 * inv;
        sdir[2 * EB + e] = r2 * inv;
        float cw = 0.5f * (__cosf(dist * 0.31415926535897931f) + 1.0f);
        scm[e] = (dist <= 10.0f) ? cw : 0.0f;
    }
    __syncthreads();

    int gi_[2]; float dist_[2];
#pragma unroll
    for (int mi = 0; mi < 2; mi++) {
        int e = (wid * 2 + mi) * 16 + c;
        gi_[mi] = sgi[e];
        dist_[mi] = sdist[e];
    }

    short8 afrC[2][4];      // m1 fragments cached across both n-passes
    floatx4 acc[2][4];      // 32 AGPR
#pragma unroll
    for (int mi = 0; mi < 2; mi++)
#pragma unroll
        for (int n = 0; n < 4; n++) acc[mi][n] = (floatx4)0.f;

    // ---- pass 1: compute m1 fragments + MFMA over features n in [0,4) ----
#pragma unroll
    for (int ch = 0; ch < 4; ch++) {
        int kb = ch * 32 + quad * 8;
        float4 wd0 = *(const float4*)(wdrow + kb);
        float4 wd1 = *(const float4*)(wdrow + kb + 4);
#pragma unroll
        for (int mi = 0; mi < 2; mi++) {
            int q = wid * 2 + mi;
            float dist = dist_[mi];
            const float4* ap = (const float4*)(Ag + gi_[mi] * HD + kb);
            float4 a0 = ap[0], a1 = ap[1];
            const float4* bp4 = (const float4*)(Bq + (q0 + q) * HD + kb);
            float4 b0 = bp4[0], b1 = bp4[1];
            short8 v;
            v[0] = f2bf(silu_f(a0.x + b0.x + dist * wd0.x));
            v[1] = f2bf(silu_f(a0.y + b0.y + dist * wd0.y));
            v[2] = f2bf(silu_f(a0.z + b0.z + dist * wd0.z));
            v[3] = f2bf(silu_f(a0.w + b0.w + dist * wd0.w));
            v[4] = f2bf(silu_f(a1.x + b1.x + dist * wd1.x));
            v[5] = f2bf(silu_f(a1.y + b1.y + dist * wd1.y));
            v[6] = f2bf(silu_f(a1.z + b1.z + dist * wd1.z));
            v[7] = f2bf(silu_f(a1.w + b1.w + dist * wd1.w));
            afrC[mi][ch] = v;
        }
#pragma unroll
        for (int n = 0; n < 4; n++) {
            short8 bfr = *(const short8*)(wsT + (n * 16 + c) * HD + kb);
            acc[0][n] = __builtin_amdgcn_mfma_f32_16x16x32_bf16(afrC[0][ch], bfr, acc[0][n], 0, 0, 0);
            acc[1][n] = __builtin_amdgcn_mfma_f32_16x16x32_bf16(afrC[1][ch], bfr, acc[1][n], 0, 0, 0);
        }
    }

    // ---- epilogue for a 4-feature-block half; NB=0 or 4 ----
#pragma unroll
    for (int half = 0; half < 2; half++) {
        if (half == 1) {
            // pass 2: reuse cached fragments, features n in [4,8)
#pragma unroll
            for (int mi = 0; mi < 2; mi++)
#pragma unroll
                for (int n = 0; n < 4; n++) acc[mi][n] = (floatx4)0.f;
#pragma unroll
            for (int ch = 0; ch < 4; ch++) {
                int kb = ch * 32 + quad * 8;
#pragma unroll
                for (int n = 0; n < 4; n++) {
                    short8 bfr = *(const short8*)(wsT + ((n + 4) * 16 + c) * HD + kb);
                    acc[0][n] = __builtin_amdgcn_mfma_f32_16x16x32_bf16(afrC[0][ch], bfr, acc[0][n], 0, 0, 0);
                    acc[1][n] = __builtin_amdgcn_mfma_f32_16x16x32_bf16(afrC[1][ch], bfr, acc[1][n], 0, 0, 0);
                }
            }
        }
        int nb = half * 4;
#pragma unroll
        for (int mi = 0; mi < 2; mi++) {
            int q = wid * 2 + mi;
            int ebase = q * 16;
            float cmr[4];
#pragma unroll
            for (int r = 0; r < 4; r++) cmr[r] = scm[ebase + quad * 4 + r];
            float apc[4][OUTT];
#pragma unroll
            for (int r = 0; r < 4; r++)
#pragma unroll
                for (int t = 0; t < OUTT; t++) apc[r][t] = 0.f;
#pragma unroll
            for (int n = 0; n < 4; n++) {
                int f = (n + nb) * 16 + c;
                float be2v = b2v[f];
                float wcv[OUTT];
                if (FIN) {
#pragma unroll
                    for (int t = 0; t < OUTT; t++) wcv[t] = Wc[f * 5 + t];
                } else {
                    wcv[0] = Wc[f];
                }
                float cs = 0.f;
#pragma unroll
                for (int r = 0; r < 4; r++) {
                    float v = silu_f(acc[mi][n][r] + be2v) * cmr[r];
                    cs += v;
#pragma unroll
                    for (int t = 0; t < OUTT; t++) apc[r][t] += v * wcv[t];
                }
                cs += __shfl_xor(cs, 16, 64);
                cs += __shfl_xor(cs, 32, 64);
                if (!FIN && lane < 16) maggr[(q0 + q) * HD + f] = cs * 0.0625f;
            }
#pragma unroll
            for (int t = 0; t < OUTT; t++) {
#pragma unroll
                for (int r = 0; r < 4; r++) {
                    float v = apc[r][t];
                    v += __shfl_xor(v, 1, 64);
                    v += __shfl_xor(v, 2, 64);
                    v += __shfl_xor(v, 4, 64);
                    v += __shfl_xor(v, 8, 64);
                    if (c == 0) {
                        int idx = (ebase + quad * 4 + r) * OUTT + t;
                        if (half == 0) scoef[idx] = v;
                        else scoef[idx] += v;
                    }
                }
            }
        }
    }
    __syncthreads();

    if (tid < QB * 3 * OUTT) {
        int qq = tid / (3 * OUTT), rem = tid % (3 * OUTT), t = rem / 3, c2 = rem % 3;
        float cbv = cbp[t];
        float s = 0.f;
#pragma unroll 4
        for (int r = 0; r < 16; r++) {
            int ee = qq * 16 + r;
            s += (scoef[ee * OUTT + t] + cbv) * sdir[c2 * EB + ee];
        }
        float dd = s * 0.0625f;
        if (FIN) out[(q0 + qq) * 15 + t * 3 + c2] = xs[qq * 3 + c2] + dd - qp[(q0 + qq) * 3 + c2];
        else x_q[(q0 + qq) * 3 + c2] = xs[qq * 3 + c2] + dd;
    }
}

extern "C" void kernel_launch(void* const* d_in, const int* in_sizes, int n_in,
                              void* d_out, int out_size, void* d_ws, size_t ws_size,
                              hipStream_t stream) {
    float* out = (float*)d_out;
    int fill_blocks = (out_size + 255) / 256;

    static const int exp_sz[16] = { 49152, 524288, 1536, 131584, 512, 65536, 512, 384,
                                    3, 640, 5, 131072, 512, 65536, 512, 524288 };
    bool ok = (n_in == 16);
    for (int i = 0; ok && i < 16; i++) if (in_sizes[i] != exp_sz[i]) ok = false;
    if (!ok || ws_size < (size_t)40 * 1024 * 1024) {
        k_fillf<<<fill_blocks, 256, 0, stream>>>(out, 777.0f, out_size);
        return;
    }

    const float* qp    = (const float*)d_in[0];
    const float* codes = (const float*)d_in[1];
    const float* gridp = (const float*)d_in[2];
    const float* eW1   = (const float*)d_in[3];
    const float* eb1   = (const float*)d_in[4];
    const float* eW2   = (const float*)d_in[5];
    const float* eb2   = (const float*)d_in[6];
    const float* cW    = (const float*)d_in[7];
    const float* cb    = (const float*)d_in[8];
    const float* fcW   = (const float*)d_in[9];
    const float* fcb   = (const float*)d_in[10];
    const float* nW1   = (const float*)d_in[11];
    const float* nb1   = (const float*)d_in[12];
    const float* nW2   = (const float*)d_in[13];
    const float* nb2   = (const float*)d_in[14];
    const int*   erow  = (const int*)d_in[15];

    float* ws = (float*)d_ws;
    float* x_q  = ws;  ws += N_PTS * 3;
    float* h_q  = ws;  ws += N_PTS * HD;
    float* hg_a = ws;  ws += N_GRID * HD;
    float* hg_b = ws;  ws += N_GRID * HD;
    float* A_g  = ws;  ws += N_GRID * HD;
    float* Bqb  = ws;  ws += N_PTS * HD;
    float* mgb  = ws;  ws += N_PTS * HD;
    short* wsT  = (short*)ws;   // 4 layers x 16384 bf16

    k_init<<<2048, 256, 0, stream>>>(qp, codes, x_q, hg_a, h_q, Bqb);
    k_prep<<<(4 * HD * HD + 255) / 256, 256, 0, stream>>>(eW2, wsT);

    float* hg_cur = hg_a;
    float* hg_next = hg_b;
    for (int i = 0; i < 4; i++) {
        int fin = (i == 3);
        const float* W1l = eW1 + i * 257 * 128;
        k_ga<<<N_GRID / 32, 256, 0, stream>>>(hg_cur, A_g, W1l, eb1 + i * 128,
                                              nW1 + i * 256 * 128, nb1 + i * 128,
                                              nW2 + i * 16384, nb2 + i * 128,
                                              fin ? 0 : 1, hg_next);
        if (i > 0) {
            int p = i - 1;   // node weights of previous layer; Bq weights of this layer
            k_nb<<<N_PTS / 32, 256, 0, stream>>>(h_q, mgb,
                                                 nW1 + p * 256 * 128, nb1 + p * 128,
                                                 nW2 + p * 16384, nb2 + p * 128,
                                                 W1l + 128 * 128, Bqb);
        }
        if (!fin)
            k_edge<1, false><<<N_PTS / QB, 256, 0, stream>>>(A_g, Bqb, x_q,
                W1l + 256 * 128, wsT + i * 16384, eb2 + i * 128,
                cW + i * 128, cb + i, erow, gridp, qp, out, mgb);
        else
            k_edge<5, true><<<N_PTS / QB, 256, 0, stream>>>(A_g, Bqb, x_q,
                W1l + 256 * 128, wsT + i * 16384, eb2 + i * 128,
                fcW, fcb, erow, gridp, qp, out, mgb);
        float* tmp = hg_cur; hg_cur = hg_next; hg_next = tmp;
    }
}

// Round 16
// 615.549 us; speedup vs baseline: 1.0448x; 1.0448x over previous
//
#include <hip/hip_runtime.h>
#include <hip/hip_bf16.h>

typedef unsigned short u16;
typedef unsigned int u32;
typedef __attribute__((ext_vector_type(8))) short short8;
typedef __attribute__((ext_vector_type(4))) float floatx4;

#define N_PTS 16384
#define N_GRID 4096
#define GPTS 512
#define HD 128
#define DEG 16
#define QB 8
#define EB 128
#define EBLK (N_PTS / QB)   // 2048 edge blocks

__device__ __forceinline__ float silu_f(float x) { return x / (1.0f + __expf(-x)); }
__device__ __forceinline__ short f2bf(float x) { return (short)__bfloat16_as_ushort(__float2bfloat16(x)); }

__global__ void k_fillf(float* out, float v, int n) {
    int i = blockIdx.x * blockDim.x + threadIdx.x;
    if (i < n) out[i] = v;
}

__global__ void k_init(const float* __restrict__ qp, const float* __restrict__ codes,
                       float* __restrict__ x_q, float* __restrict__ h_g, float* __restrict__ h_q,
                       float* __restrict__ Bq) {
    int stride = gridDim.x * blockDim.x;
    int i0 = blockIdx.x * blockDim.x + threadIdx.x;
    for (int i = i0; i < N_PTS * 3; i += stride) x_q[i] = qp[i];
    for (int i = i0; i < N_GRID * HD; i += stride) h_g[i] = codes[i];
    for (int i = i0; i < N_PTS * HD; i += stride) { h_q[i] = 0.0f; Bq[i] = 0.0f; }
}

// transpose We2 -> bf16 wsT[layer][f*128+k]
__global__ void k_prep(const float* __restrict__ eW2, short* __restrict__ wsT) {
    int idx = blockIdx.x * blockDim.x + threadIdx.x;
    if (idx >= 4 * HD * HD) return;
    int l = idx >> 14, rem = idx & 16383, f = rem >> 7, k = rem & 127;
    wsT[idx] = f2bf(eW2[l * 16384 + k * HD + f]);
}

// ---------------- ga body (device fn): grid-node A + h update, 32 nodes/block ----------------
__device__ __forceinline__ void ga_body(
    float* T1, float* T2, int n0, int tid,
    const float* __restrict__ hg, float* __restrict__ Ag,
    const float* __restrict__ W1top, const float* __restrict__ b1,
    const float* __restrict__ Wn1top, const float* __restrict__ bn1,
    const float* __restrict__ Wn2, const float* __restrict__ bn2,
    int updateH, float* __restrict__ hg_out) {
    int f0 = (tid & 31) * 4;
    int ng = (tid >> 5) * 4;
    {
        int q = tid & 31, j0 = (tid >> 5) * 16;
#pragma unroll
        for (int s = 0; s < 4; s++) {
            float4 v = *(const float4*)&hg[(n0 + q) * HD + j0 + s * 4];
            T1[(j0 + s * 4 + 0) * 36 + q] = v.x;
            T1[(j0 + s * 4 + 1) * 36 + q] = v.y;
            T1[(j0 + s * 4 + 2) * 36 + q] = v.z;
            T1[(j0 + s * 4 + 3) * 36 + q] = v.w;
        }
    }
    __syncthreads();
    float4 acc[4];
    {
        float4 bv = *(const float4*)&b1[f0];
#pragma unroll
        for (int qq = 0; qq < 4; qq++) acc[qq] = bv;
#pragma unroll 4
        for (int j = 0; j < HD; j++) {
            float4 a = *(const float4*)&T1[j * 36 + ng];
            float4 w = *(const float4*)&W1top[j * HD + f0];
            acc[0].x += a.x * w.x; acc[0].y += a.x * w.y; acc[0].z += a.x * w.z; acc[0].w += a.x * w.w;
            acc[1].x += a.y * w.x; acc[1].y += a.y * w.y; acc[1].z += a.y * w.z; acc[1].w += a.y * w.w;
            acc[2].x += a.z * w.x; acc[2].y += a.z * w.y; acc[2].z += a.z * w.z; acc[2].w += a.z * w.w;
            acc[3].x += a.w * w.x; acc[3].y += a.w * w.y; acc[3].z += a.w * w.z; acc[3].w += a.w * w.w;
        }
#pragma unroll
        for (int qq = 0; qq < 4; qq++)
            *(float4*)&Ag[(n0 + ng + qq) * HD + f0] = acc[qq];
    }
    if (updateH) {
        float4 bv = *(const float4*)&bn1[f0];
#pragma unroll
        for (int qq = 0; qq < 4; qq++) acc[qq] = bv;
#pragma unroll 4
        for (int j = 0; j < HD; j++) {
            float4 a = *(const float4*)&T1[j * 36 + ng];
            float4 w = *(const float4*)&Wn1top[j * HD + f0];
            acc[0].x += a.x * w.x; acc[0].y += a.x * w.y; acc[0].z += a.x * w.z; acc[0].w += a.x * w.w;
            acc[1].x += a.y * w.x; acc[1].y += a.y * w.y; acc[1].z += a.y * w.z; acc[1].w += a.y * w.w;
            acc[2].x += a.z * w.x; acc[2].y += a.z * w.y; acc[2].z += a.z * w.z; acc[2].w += a.z * w.w;
            acc[3].x += a.w * w.x; acc[3].y += a.w * w.y; acc[3].z += a.w * w.z; acc[3].w += a.w * w.w;
        }
#pragma unroll
        for (int qq = 0; qq < 4; qq++) {
            T2[(f0 + 0) * 36 + ng + qq] = silu_f(acc[qq].x);
            T2[(f0 + 1) * 36 + ng + qq] = silu_f(acc[qq].y);
            T2[(f0 + 2) * 36 + ng + qq] = silu_f(acc[qq].z);
            T2[(f0 + 3) * 36 + ng + qq] = silu_f(acc[qq].w);
        }
        __syncthreads();
        bv = *(const float4*)&bn2[f0];
#pragma unroll
        for (int qq = 0; qq < 4; qq++) acc[qq] = bv;
#pragma unroll 4
        for (int j = 0; j < HD; j++) {
            float4 a = *(const float4*)&T2[j * 36 + ng];
            float4 w = *(const float4*)&Wn2[j * HD + f0];
            acc[0].x += a.x * w.x; acc[0].y += a.x * w.y; acc[0].z += a.x * w.z; acc[0].w += a.x * w.w;
            acc[1].x += a.y * w.x; acc[1].y += a.y * w.y; acc[1].z += a.y * w.z; acc[1].w += a.y * w.w;
            acc[2].x += a.z * w.x; acc[2].y += a.z * w.y; acc[2].z += a.z * w.z; acc[2].w += a.z * w.w;
            acc[3].x += a.w * w.x; acc[3].y += a.w * w.y; acc[3].z += a.w * w.z; acc[3].w += a.w * w.w;
        }
#pragma unroll
        for (int qq = 0; qq < 4; qq++) {
            float4 h;
            h.x = T1[(f0 + 0) * 36 + ng + qq] + acc[qq].x;
            h.y = T1[(f0 + 1) * 36 + ng + qq] + acc[qq].y;
            h.z = T1[(f0 + 2) * 36 + ng + qq] + acc[qq].z;
            h.w = T1[(f0 + 3) * 36 + ng + qq] + acc[qq].w;
            *(float4*)&hg_out[(n0 + ng + qq) * HD + f0] = h;
        }
    }
}

// ---------------- standalone ga (layer 0) ----------------
__global__ __launch_bounds__(256) void k_ga(
    const float* __restrict__ hg, float* __restrict__ Ag,
    const float* __restrict__ W1top, const float* __restrict__ b1,
    const float* __restrict__ Wn1top, const float* __restrict__ bn1,
    const float* __restrict__ Wn2, const float* __restrict__ bn2,
    int updateH, float* __restrict__ hg_out) {
    __shared__ float T1[HD * 36];
    __shared__ float T2[HD * 36];
    ga_body(T1, T2, blockIdx.x * 32, threadIdx.x, hg, Ag, W1top, b1,
            Wn1top, bn1, Wn2, bn2, updateH, hg_out);
}

// ---------------- fused node MLP + Bq: h += MLP(h,mg); Bq = h_new @ W1mid ----------------
__global__ __launch_bounds__(256) void k_nb(
    float* __restrict__ hq, const float* __restrict__ mg,
    const float* __restrict__ Wn1, const float* __restrict__ bn1,
    const float* __restrict__ Wn2, const float* __restrict__ bn2,
    const float* __restrict__ W1mid, float* __restrict__ Bq) {
    __shared__ float aT[256 * 36];
    __shared__ float stT[HD * 36];
    int tid = threadIdx.x;
    int q0 = blockIdx.x * 32;
    {
        int q = tid & 31, j0 = (tid >> 5) * 16;
#pragma unroll
        for (int s = 0; s < 4; s++) {
            float4 v = *(const float4*)&hq[(q0 + q) * HD + j0 + s * 4];
            aT[(j0 + s * 4 + 0) * 36 + q] = v.x;
            aT[(j0 + s * 4 + 1) * 36 + q] = v.y;
            aT[(j0 + s * 4 + 2) * 36 + q] = v.z;
            aT[(j0 + s * 4 + 3) * 36 + q] = v.w;
            float4 m = *(const float4*)&mg[(q0 + q) * HD + j0 + s * 4];
            aT[(128 + j0 + s * 4 + 0) * 36 + q] = m.x;
            aT[(128 + j0 + s * 4 + 1) * 36 + q] = m.y;
            aT[(128 + j0 + s * 4 + 2) * 36 + q] = m.z;
            aT[(128 + j0 + s * 4 + 3) * 36 + q] = m.w;
        }
    }
    __syncthreads();
    int f0 = (tid & 31) * 4;
    int qg = (tid >> 5) * 4;
    float4 bn1v = *(const float4*)&bn1[f0];
    float4 acc[4];
#pragma unroll
    for (int qq = 0; qq < 4; qq++) acc[qq] = bn1v;
#pragma unroll 4
    for (int j = 0; j < 256; j++) {
        float4 a = *(const float4*)&aT[j * 36 + qg];
        float4 w = *(const float4*)&Wn1[j * HD + f0];
        acc[0].x += a.x * w.x; acc[0].y += a.x * w.y; acc[0].z += a.x * w.z; acc[0].w += a.x * w.w;
        acc[1].x += a.y * w.x; acc[1].y += a.y * w.y; acc[1].z += a.y * w.z; acc[1].w += a.y * w.w;
        acc[2].x += a.z * w.x; acc[2].y += a.z * w.y; acc[2].z += a.z * w.z; acc[2].w += a.z * w.w;
        acc[3].x += a.w * w.x; acc[3].y += a.w * w.y; acc[3].z += a.w * w.z; acc[3].w += a.w * w.w;
    }
#pragma unroll
    for (int qq = 0; qq < 4; qq++) {
        stT[(f0 + 0) * 36 + qg + qq] = silu_f(acc[qq].x);
        stT[(f0 + 1) * 36 + qg + qq] = silu_f(acc[qq].y);
        stT[(f0 + 2) * 36 + qg + qq] = silu_f(acc[qq].z);
        stT[(f0 + 3) * 36 + qg + qq] = silu_f(acc[qq].w);
    }
    __syncthreads();
    float4 bn2v = *(const float4*)&bn2[f0];
#pragma unroll
    for (int qq = 0; qq < 4; qq++) acc[qq] = bn2v;
#pragma unroll 4
    for (int j = 0; j < HD; j++) {
        float4 a = *(const float4*)&stT[j * 36 + qg];
        float4 w = *(const float4*)&Wn2[j * HD + f0];
        acc[0].x += a.x * w.x; acc[0].y += a.x * w.y; acc[0].z += a.x * w.z; acc[0].w += a.x * w.w;
        acc[1].x += a.y * w.x; acc[1].y += a.y * w.y; acc[1].z += a.y * w.z; acc[1].w += a.y * w.w;
        acc[2].x += a.z * w.x; acc[2].y += a.z * w.y; acc[2].z += a.z * w.z; acc[2].w += a.z * w.w;
        acc[3].x += a.w * w.x; acc[3].y += a.w * w.y; acc[3].z += a.w * w.z; acc[3].w += a.w * w.w;
    }
#pragma unroll
    for (int qq = 0; qq < 4; qq++) {
        float4 h;
        h.x = aT[(f0 + 0) * 36 + qg + qq] + acc[qq].x;
        h.y = aT[(f0 + 1) * 36 + qg + qq] + acc[qq].y;
        h.z = aT[(f0 + 2) * 36 + qg + qq] + acc[qq].z;
        h.w = aT[(f0 + 3) * 36 + qg + qq] + acc[qq].w;
        *(float4*)&hq[(q0 + qg + qq) * HD + f0] = h;
        aT[(f0 + 0) * 36 + qg + qq] = h.x;
        aT[(f0 + 1) * 36 + qg + qq] = h.y;
        aT[(f0 + 2) * 36 + qg + qq] = h.z;
        aT[(f0 + 3) * 36 + qg + qq] = h.w;
    }
    __syncthreads();
    float4 acc2[4] = {};
#pragma unroll 4
    for (int j = 0; j < HD; j++) {
        float4 a = *(const float4*)&aT[j * 36 + qg];
        float4 w = *(const float4*)&W1mid[j * HD + f0];
        acc2[0].x += a.x * w.x; acc2[0].y += a.x * w.y; acc2[0].z += a.x * w.z; acc2[0].w += a.x * w.w;
        acc2[1].x += a.y * w.x; acc2[1].y += a.y * w.y; acc2[1].z += a.y * w.z; acc2[1].w += a.y * w.w;
        acc2[2].x += a.z * w.x; acc2[2].y += a.z * w.y; acc2[2].z += a.z * w.z; acc2[2].w += a.z * w.w;
        acc2[3].x += a.w * w.x; acc2[3].y += a.w * w.y; acc2[3].z += a.w * w.z; acc2[3].w += a.w * w.w;
    }
#pragma unroll
    for (int qq = 0; qq < 4; qq++)
        *(float4*)&Bq[(q0 + qg + qq) * HD + f0] = acc2[qq];
}

// ---------------- fused: edge blocks [0,2048) + ga(layer+1) blocks [2048,2176) ----------------
template <int OUTT, bool FIN, bool GA>
__global__ __launch_bounds__(256, 3) void k_edge_ga(
    const float* __restrict__ Ag, const float* __restrict__ Bq, float* __restrict__ x_q,
    const float* __restrict__ wdrow, const short* __restrict__ wsT,
    const float* __restrict__ b2v, const float* __restrict__ Wc, const float* __restrict__ cbp,
    const int* __restrict__ erow, const float* __restrict__ gridp,
    const float* __restrict__ qp, float* __restrict__ out, float* __restrict__ maggr,
    const float* __restrict__ hg, float* __restrict__ Ag2,
    const float* __restrict__ W1top, const float* __restrict__ b1,
    const float* __restrict__ Wn1top, const float* __restrict__ bn1,
    const float* __restrict__ Wn2g, const float* __restrict__ bn2g,
    int updateH, float* __restrict__ hg_out) {
    __shared__ float S1[HD * 36];
    __shared__ float S2[HD * 36];
    int tid = threadIdx.x;

    if (GA && blockIdx.x >= EBLK) {
        ga_body(S1, S2, (blockIdx.x - EBLK) * 32, tid, hg, Ag2, W1top, b1,
                Wn1top, bn1, Wn2g, bn2g, updateH, hg_out);
        return;
    }

    float* sdist = S1;                 // 128
    float* scm   = S1 + 128;           // 128
    float* sdir  = S1 + 256;           // 384
    float* xs    = S1 + 640;           // 24
    float* scoef = S1 + 704;           // <= 640
    int*   sgi   = (int*)S2;           // 128

    int q0 = blockIdx.x * QB;
    int wid = tid >> 6, lane = tid & 63, quad = lane >> 4, c = lane & 15;

    if (tid < QB * 3) xs[tid] = x_q[q0 * 3 + tid];
    __syncthreads();
    if (tid < EB) {
        int e = tid, q = e >> 4;
        int gi = erow[q0 * DEG + e] - N_PTS;
        sgi[e] = gi;
        int gl = gi & (GPTS - 1);
        float r0 = gridp[gl * 3 + 0] - xs[q * 3 + 0];
        float r1 = gridp[gl * 3 + 1] - xs[q * 3 + 1];
        float r2 = gridp[gl * 3 + 2] - xs[q * 3 + 2];
        float dist = sqrtf(r0 * r0 + r1 * r1 + r2 * r2);
        float inv = 1.0f / (dist + 1e-8f);
        sdist[e] = dist;
        sdir[0 * EB + e] = r0 * inv;
        sdir[1 * EB + e] = r1 * inv;
        sdir[2 * EB + e] = r2 * inv;
        float cw = 0.5f * (__cosf(dist * 0.31415926535897931f) + 1.0f);
        scm[e] = (dist <= 10.0f) ? cw : 0.0f;
    }
    __syncthreads();

    int gi_[2]; float dist_[2];
#pragma unroll
    for (int mi = 0; mi < 2; mi++) {
        int e = (wid * 2 + mi) * 16 + c;
        gi_[mi] = sgi[e];
        dist_[mi] = sdist[e];
    }

    floatx4 acc[2][8];
#pragma unroll
    for (int mi = 0; mi < 2; mi++)
#pragma unroll
        for (int n = 0; n < 8; n++) acc[mi][n] = (floatx4)0.f;

#pragma unroll
    for (int ch = 0; ch < 4; ch++) {
        int kb = ch * 32 + quad * 8;
        float4 wd0 = *(const float4*)(wdrow + kb);
        float4 wd1 = *(const float4*)(wdrow + kb + 4);
        short8 afr[2];
#pragma unroll
        for (int mi = 0; mi < 2; mi++) {
            int q = wid * 2 + mi;
            float dist = dist_[mi];
            const float4* ap = (const float4*)(Ag + gi_[mi] * HD + kb);
            float4 a0 = ap[0], a1 = ap[1];
            const float4* bp4 = (const float4*)(Bq + (q0 + q) * HD + kb);
            float4 b0 = bp4[0], b1 = bp4[1];
            short8 v;
            v[0] = f2bf(silu_f(a0.x + b0.x + dist * wd0.x));
            v[1] = f2bf(silu_f(a0.y + b0.y + dist * wd0.y));
            v[2] = f2bf(silu_f(a0.z + b0.z + dist * wd0.z));
            v[3] = f2bf(silu_f(a0.w + b0.w + dist * wd0.w));
            v[4] = f2bf(silu_f(a1.x + b1.x + dist * wd1.x));
            v[5] = f2bf(silu_f(a1.y + b1.y + dist * wd1.y));
            v[6] = f2bf(silu_f(a1.z + b1.z + dist * wd1.z));
            v[7] = f2bf(silu_f(a1.w + b1.w + dist * wd1.w));
            afr[mi] = v;
        }
#pragma unroll
        for (int n = 0; n < 8; n++) {
            short8 bfr = *(const short8*)(wsT + (n * 16 + c) * HD + kb);
            acc[0][n] = __builtin_amdgcn_mfma_f32_16x16x32_bf16(afr[0], bfr, acc[0][n], 0, 0, 0);
            acc[1][n] = __builtin_amdgcn_mfma_f32_16x16x32_bf16(afr[1], bfr, acc[1][n], 0, 0, 0);
        }
    }

#pragma unroll
    for (int mi = 0; mi < 2; mi++) {
        int q = wid * 2 + mi;
        int ebase = q * 16;
        float cmr[4];
#pragma unroll
        for (int r = 0; r < 4; r++) cmr[r] = scm[ebase + quad * 4 + r];
        float apc[4][OUTT];
#pragma unroll
        for (int r = 0; r < 4; r++)
#pragma unroll
            for (int t = 0; t < OUTT; t++) apc[r][t] = 0.f;
#pragma unroll
        for (int n = 0; n < 8; n++) {
            int f = n * 16 + c;
            float be2v = b2v[f];
            float wcv[OUTT];
            if (FIN) {
#pragma unroll
                for (int t = 0; t < OUTT; t++) wcv[t] = Wc[f * 5 + t];
            } else {
                wcv[0] = Wc[f];
            }
            float cs = 0.f;
#pragma unroll
            for (int r = 0; r < 4; r++) {
                float v = silu_f(acc[mi][n][r] + be2v) * cmr[r];
                cs += v;
#pragma unroll
                for (int t = 0; t < OUTT; t++) apc[r][t] += v * wcv[t];
            }
            cs += __shfl_xor(cs, 16, 64);
            cs += __shfl_xor(cs, 32, 64);
            if (!FIN && lane < 16) maggr[(q0 + q) * HD + f] = cs * 0.0625f;
        }
#pragma unroll
        for (int t = 0; t < OUTT; t++) {
#pragma unroll
            for (int r = 0; r < 4; r++) {
                float v = apc[r][t];
                v += __shfl_xor(v, 1, 64);
                v += __shfl_xor(v, 2, 64);
                v += __shfl_xor(v, 4, 64);
                v += __shfl_xor(v, 8, 64);
                if (c == 0) scoef[(ebase + quad * 4 + r) * OUTT + t] = v;
            }
        }
    }
    __syncthreads();

    if (tid < QB * 3 * OUTT) {
        int qq = tid / (3 * OUTT), rem = tid % (3 * OUTT), t = rem / 3, c2 = rem % 3;
        float cbv = cbp[t];
        float s = 0.f;
#pragma unroll 4
        for (int r = 0; r < 16; r++) {
            int ee = qq * 16 + r;
            s += (scoef[ee * OUTT + t] + cbv) * sdir[c2 * EB + ee];
        }
        float dd = s * 0.0625f;
        if (FIN) out[(q0 + qq) * 15 + t * 3 + c2] = xs[qq * 3 + c2] + dd - qp[(q0 + qq) * 3 + c2];
        else x_q[(q0 + qq) * 3 + c2] = xs[qq * 3 + c2] + dd;
    }
}

extern "C" void kernel_launch(void* const* d_in, const int* in_sizes, int n_in,
                              void* d_out, int out_size, void* d_ws, size_t ws_size,
                              hipStream_t stream) {
    float* out = (float*)d_out;
    int fill_blocks = (out_size + 255) / 256;

    static const int exp_sz[16] = { 49152, 524288, 1536, 131584, 512, 65536, 512, 384,
                                    3, 640, 5, 131072, 512, 65536, 512, 524288 };
    bool ok = (n_in == 16);
    for (int i = 0; ok && i < 16; i++) if (in_sizes[i] != exp_sz[i]) ok = false;
    if (!ok || ws_size < (size_t)40 * 1024 * 1024) {
        k_fillf<<<fill_blocks, 256, 0, stream>>>(out, 777.0f, out_size);
        return;
    }

    const float* qp    = (const float*)d_in[0];
    const float* codes = (const float*)d_in[1];
    const float* gridp = (const float*)d_in[2];
    const float* eW1   = (const float*)d_in[3];
    const float* eb1   = (const float*)d_in[4];
    const float* eW2   = (const float*)d_in[5];
    const float* eb2   = (const float*)d_in[6];
    const float* cW    = (const float*)d_in[7];
    const float* cb    = (const float*)d_in[8];
    const float* fcW   = (const float*)d_in[9];
    const float* fcb   = (const float*)d_in[10];
    const float* nW1   = (const float*)d_in[11];
    const float* nb1   = (const float*)d_in[12];
    const float* nW2   = (const float*)d_in[13];
    const float* nb2   = (const float*)d_in[14];
    const int*   erow  = (const int*)d_in[15];

    float* ws = (float*)d_ws;
    float* x_q  = ws;  ws += N_PTS * 3;
    float* h_q  = ws;  ws += N_PTS * HD;
    float* hg_a = ws;  ws += N_GRID * HD;
    float* hg_b = ws;  ws += N_GRID * HD;
    float* Ag0  = ws;  ws += N_GRID * HD;
    float* Ag1  = ws;  ws += N_GRID * HD;
    float* Bqb  = ws;  ws += N_PTS * HD;
    float* mgb  = ws;  ws += N_PTS * HD;
    short* wsT  = (short*)ws;   // 4 layers x 16384 bf16
    float* Agb[2] = { Ag0, Ag1 };

    k_init<<<2048, 256, 0, stream>>>(qp, codes, x_q, hg_a, h_q, Bqb);
    k_prep<<<(4 * HD * HD + 255) / 256, 256, 0, stream>>>(eW2, wsT);

    // layer-0 ga standalone: A_g(0), h_g(1)
    k_ga<<<N_GRID / 32, 256, 0, stream>>>(hg_a, Agb[0], eW1, eb1,
                                          nW1, nb1, nW2, nb2, 1, hg_b);
    float* hg_cur = hg_b;       // h_g for layer 1
    float* hg_next = hg_a;

    for (int i = 0; i < 4; i++) {
        int fin = (i == 3);
        const float* W1l = eW1 + i * 257 * 128;
        if (i > 0) {
            int p = i - 1;
            k_nb<<<N_PTS / 32, 256, 0, stream>>>(h_q, mgb,
                                                 nW1 + p * 256 * 128, nb1 + p * 128,
                                                 nW2 + p * 16384, nb2 + p * 128,
                                                 W1l + 128 * 128, Bqb);
        }
        if (!fin) {
            int L = i + 1;      // ga layer riding along
            const float* W1n = eW1 + L * 257 * 128;
            k_edge_ga<1, false, true><<<EBLK + N_GRID / 32, 256, 0, stream>>>(
                Agb[i & 1], Bqb, x_q, W1l + 256 * 128, wsT + i * 16384, eb2 + i * 128,
                cW + i * 128, cb + i, erow, gridp, qp, out, mgb,
                hg_cur, Agb[L & 1], W1n, eb1 + L * 128,
                nW1 + L * 256 * 128, nb1 + L * 128, nW2 + L * 16384, nb2 + L * 128,
                (L < 3) ? 1 : 0, hg_next);
            float* tmp = hg_cur; hg_cur = hg_next; hg_next = tmp;
        } else {
            k_edge_ga<5, true, false><<<EBLK, 256, 0, stream>>>(
                Agb[i & 1], Bqb, x_q, W1l + 256 * 128, wsT + i * 16384, eb2 + i * 128,
                fcW, fcb, erow, gridp, qp, out, mgb,
                nullptr, nullptr, nullptr, nullptr,
                nullptr, nullptr, nullptr, nullptr, 0, nullptr);
        }
    }
}

// Round 17
// 603.645 us; speedup vs baseline: 1.0654x; 1.0197x over previous
//
#include <hip/hip_runtime.h>
#include <hip/hip_bf16.h>

typedef unsigned short u16;
typedef unsigned int u32;
typedef __attribute__((ext_vector_type(8))) short short8;
typedef __attribute__((ext_vector_type(4))) float floatx4;

#define N_PTS 16384
#define N_GRID 4096
#define GPTS 512
#define HD 128
#define DEG 16
#define QB 8
#define EB 128
#define EBLK (N_PTS / QB)   // 2048 edge blocks
#define GABLK (N_GRID / 16) // 256 ga blocks (16-node tile)

__device__ __forceinline__ float silu_f(float x) { return x / (1.0f + __expf(-x)); }
__device__ __forceinline__ short f2bf(float x) { return (short)__bfloat16_as_ushort(__float2bfloat16(x)); }

__global__ void k_fillf(float* out, float v, int n) {
    int i = blockIdx.x * blockDim.x + threadIdx.x;
    if (i < n) out[i] = v;
}

__global__ void k_init(const float* __restrict__ qp, const float* __restrict__ codes,
                       float* __restrict__ x_q, float* __restrict__ h_g, float* __restrict__ h_q,
                       float* __restrict__ Bq) {
    int stride = gridDim.x * blockDim.x;
    int i0 = blockIdx.x * blockDim.x + threadIdx.x;
    for (int i = i0; i < N_PTS * 3; i += stride) x_q[i] = qp[i];
    for (int i = i0; i < N_GRID * HD; i += stride) h_g[i] = codes[i];
    for (int i = i0; i < N_PTS * HD; i += stride) { h_q[i] = 0.0f; Bq[i] = 0.0f; }
}

// transpose We2 -> bf16 wsT[layer][f*128+k]
__global__ void k_prep(const float* __restrict__ eW2, short* __restrict__ wsT) {
    int idx = blockIdx.x * blockDim.x + threadIdx.x;
    if (idx >= 4 * HD * HD) return;
    int l = idx >> 14, rem = idx & 16383, f = rem >> 7, k = rem & 127;
    wsT[idx] = f2bf(eW2[l * 16384 + k * HD + f]);
}

// ---------------- ga body: 16 nodes/block, T1/T2 = 128*20 floats (10.2 KB each) ----------------
__device__ __forceinline__ void ga_body(
    float* T1, float* T2, int n0, int tid,
    const float* __restrict__ hg, float* __restrict__ Ag,
    const float* __restrict__ W1top, const float* __restrict__ b1,
    const float* __restrict__ Wn1top, const float* __restrict__ bn1,
    const float* __restrict__ Wn2, const float* __restrict__ bn2,
    int updateH, float* __restrict__ hg_out) {
    int f0 = (tid & 31) * 4;
    int n2 = (tid >> 5) * 2;     // node pair 0,2,..,14
    {
        int node = tid & 15, j0 = (tid >> 4) * 8;
        float4 v0 = *(const float4*)&hg[(n0 + node) * HD + j0];
        float4 v1 = *(const float4*)&hg[(n0 + node) * HD + j0 + 4];
        T1[(j0 + 0) * 20 + node] = v0.x;
        T1[(j0 + 1) * 20 + node] = v0.y;
        T1[(j0 + 2) * 20 + node] = v0.z;
        T1[(j0 + 3) * 20 + node] = v0.w;
        T1[(j0 + 4) * 20 + node] = v1.x;
        T1[(j0 + 5) * 20 + node] = v1.y;
        T1[(j0 + 6) * 20 + node] = v1.z;
        T1[(j0 + 7) * 20 + node] = v1.w;
    }
    __syncthreads();
    float4 acc[2];
    {
        float4 bv = *(const float4*)&b1[f0];
        acc[0] = bv; acc[1] = bv;
#pragma unroll 4
        for (int j = 0; j < HD; j++) {
            float2 a = *(const float2*)&T1[j * 20 + n2];
            float4 w = *(const float4*)&W1top[j * HD + f0];
            acc[0].x += a.x * w.x; acc[0].y += a.x * w.y; acc[0].z += a.x * w.z; acc[0].w += a.x * w.w;
            acc[1].x += a.y * w.x; acc[1].y += a.y * w.y; acc[1].z += a.y * w.z; acc[1].w += a.y * w.w;
        }
        *(float4*)&Ag[(n0 + n2 + 0) * HD + f0] = acc[0];
        *(float4*)&Ag[(n0 + n2 + 1) * HD + f0] = acc[1];
    }
    if (updateH) {
        float4 bv = *(const float4*)&bn1[f0];
        acc[0] = bv; acc[1] = bv;
#pragma unroll 4
        for (int j = 0; j < HD; j++) {
            float2 a = *(const float2*)&T1[j * 20 + n2];
            float4 w = *(const float4*)&Wn1top[j * HD + f0];
            acc[0].x += a.x * w.x; acc[0].y += a.x * w.y; acc[0].z += a.x * w.z; acc[0].w += a.x * w.w;
            acc[1].x += a.y * w.x; acc[1].y += a.y * w.y; acc[1].z += a.y * w.z; acc[1].w += a.y * w.w;
        }
#pragma unroll
        for (int qq = 0; qq < 2; qq++) {
            T2[(f0 + 0) * 20 + n2 + qq] = silu_f(acc[qq].x);
            T2[(f0 + 1) * 20 + n2 + qq] = silu_f(acc[qq].y);
            T2[(f0 + 2) * 20 + n2 + qq] = silu_f(acc[qq].z);
            T2[(f0 + 3) * 20 + n2 + qq] = silu_f(acc[qq].w);
        }
        __syncthreads();
        bv = *(const float4*)&bn2[f0];
        acc[0] = bv; acc[1] = bv;
#pragma unroll 4
        for (int j = 0; j < HD; j++) {
            float2 a = *(const float2*)&T2[j * 20 + n2];
            float4 w = *(const float4*)&Wn2[j * HD + f0];
            acc[0].x += a.x * w.x; acc[0].y += a.x * w.y; acc[0].z += a.x * w.z; acc[0].w += a.x * w.w;
            acc[1].x += a.y * w.x; acc[1].y += a.y * w.y; acc[1].z += a.y * w.z; acc[1].w += a.y * w.w;
        }
#pragma unroll
        for (int qq = 0; qq < 2; qq++) {
            float4 h;
            h.x = T1[(f0 + 0) * 20 + n2 + qq] + acc[qq].x;
            h.y = T1[(f0 + 1) * 20 + n2 + qq] + acc[qq].y;
            h.z = T1[(f0 + 2) * 20 + n2 + qq] + acc[qq].z;
            h.w = T1[(f0 + 3) * 20 + n2 + qq] + acc[qq].w;
            *(float4*)&hg_out[(n0 + n2 + qq) * HD + f0] = h;
        }
    }
}

// ---------------- standalone ga (layer 0) ----------------
__global__ __launch_bounds__(256) void k_ga(
    const float* __restrict__ hg, float* __restrict__ Ag,
    const float* __restrict__ W1top, const float* __restrict__ b1,
    const float* __restrict__ Wn1top, const float* __restrict__ bn1,
    const float* __restrict__ Wn2, const float* __restrict__ bn2,
    int updateH, float* __restrict__ hg_out) {
    __shared__ float T1[HD * 20];
    __shared__ float T2[HD * 20];
    ga_body(T1, T2, blockIdx.x * 16, threadIdx.x, hg, Ag, W1top, b1,
            Wn1top, bn1, Wn2, bn2, updateH, hg_out);
}

// ---------------- fused node MLP + Bq; stT aliased onto dead mg-half of aT ----------------
__global__ __launch_bounds__(256) void k_nb(
    float* __restrict__ hq, const float* __restrict__ mg,
    const float* __restrict__ Wn1, const float* __restrict__ bn1,
    const float* __restrict__ Wn2, const float* __restrict__ bn2,
    const float* __restrict__ W1mid, float* __restrict__ Bq) {
    __shared__ float aT[256 * 36];
    float* stT = aT + 128 * 36;    // rows 128..255 (mg) dead after GEMM1
    int tid = threadIdx.x;
    int q0 = blockIdx.x * 32;
    {
        int q = tid & 31, j0 = (tid >> 5) * 16;
#pragma unroll
        for (int s = 0; s < 4; s++) {
            float4 v = *(const float4*)&hq[(q0 + q) * HD + j0 + s * 4];
            aT[(j0 + s * 4 + 0) * 36 + q] = v.x;
            aT[(j0 + s * 4 + 1) * 36 + q] = v.y;
            aT[(j0 + s * 4 + 2) * 36 + q] = v.z;
            aT[(j0 + s * 4 + 3) * 36 + q] = v.w;
            float4 m = *(const float4*)&mg[(q0 + q) * HD + j0 + s * 4];
            aT[(128 + j0 + s * 4 + 0) * 36 + q] = m.x;
            aT[(128 + j0 + s * 4 + 1) * 36 + q] = m.y;
            aT[(128 + j0 + s * 4 + 2) * 36 + q] = m.z;
            aT[(128 + j0 + s * 4 + 3) * 36 + q] = m.w;
        }
    }
    __syncthreads();
    int f0 = (tid & 31) * 4;
    int qg = (tid >> 5) * 4;
    float4 bn1v = *(const float4*)&bn1[f0];
    float4 acc[4];
#pragma unroll
    for (int qq = 0; qq < 4; qq++) acc[qq] = bn1v;
#pragma unroll 4
    for (int j = 0; j < 256; j++) {
        float4 a = *(const float4*)&aT[j * 36 + qg];
        float4 w = *(const float4*)&Wn1[j * HD + f0];
        acc[0].x += a.x * w.x; acc[0].y += a.x * w.y; acc[0].z += a.x * w.z; acc[0].w += a.x * w.w;
        acc[1].x += a.y * w.x; acc[1].y += a.y * w.y; acc[1].z += a.y * w.z; acc[1].w += a.y * w.w;
        acc[2].x += a.z * w.x; acc[2].y += a.z * w.y; acc[2].z += a.z * w.z; acc[2].w += a.z * w.w;
        acc[3].x += a.w * w.x; acc[3].y += a.w * w.y; acc[3].z += a.w * w.z; acc[3].w += a.w * w.w;
    }
    __syncthreads();   // all GEMM1 reads of aT rows 128..255 complete before stT overwrite
#pragma unroll
    for (int qq = 0; qq < 4; qq++) {
        stT[(f0 + 0) * 36 + qg + qq] = silu_f(acc[qq].x);
        stT[(f0 + 1) * 36 + qg + qq] = silu_f(acc[qq].y);
        stT[(f0 + 2) * 36 + qg + qq] = silu_f(acc[qq].z);
        stT[(f0 + 3) * 36 + qg + qq] = silu_f(acc[qq].w);
    }
    __syncthreads();
    float4 bn2v = *(const float4*)&bn2[f0];
#pragma unroll
    for (int qq = 0; qq < 4; qq++) acc[qq] = bn2v;
#pragma unroll 4
    for (int j = 0; j < HD; j++) {
        float4 a = *(const float4*)&stT[j * 36 + qg];
        float4 w = *(const float4*)&Wn2[j * HD + f0];
        acc[0].x += a.x * w.x; acc[0].y += a.x * w.y; acc[0].z += a.x * w.z; acc[0].w += a.x * w.w;
        acc[1].x += a.y * w.x; acc[1].y += a.y * w.y; acc[1].z += a.y * w.z; acc[1].w += a.y * w.w;
        acc[2].x += a.z * w.x; acc[2].y += a.z * w.y; acc[2].z += a.z * w.z; acc[2].w += a.z * w.w;
        acc[3].x += a.w * w.x; acc[3].y += a.w * w.y; acc[3].z += a.w * w.z; acc[3].w += a.w * w.w;
    }
#pragma unroll
    for (int qq = 0; qq < 4; qq++) {
        float4 h;
        h.x = aT[(f0 + 0) * 36 + qg + qq] + acc[qq].x;
        h.y = aT[(f0 + 1) * 36 + qg + qq] + acc[qq].y;
        h.z = aT[(f0 + 2) * 36 + qg + qq] + acc[qq].z;
        h.w = aT[(f0 + 3) * 36 + qg + qq] + acc[qq].w;
        *(float4*)&hq[(q0 + qg + qq) * HD + f0] = h;
        aT[(f0 + 0) * 36 + qg + qq] = h.x;
        aT[(f0 + 1) * 36 + qg + qq] = h.y;
        aT[(f0 + 2) * 36 + qg + qq] = h.z;
        aT[(f0 + 3) * 36 + qg + qq] = h.w;
    }
    __syncthreads();
    float4 acc2[4] = {};
#pragma unroll 4
    for (int j = 0; j < HD; j++) {
        float4 a = *(const float4*)&aT[j * 36 + qg];
        float4 w = *(const float4*)&W1mid[j * HD + f0];
        acc2[0].x += a.x * w.x; acc2[0].y += a.x * w.y; acc2[0].z += a.x * w.z; acc2[0].w += a.x * w.w;
        acc2[1].x += a.y * w.x; acc2[1].y += a.y * w.y; acc2[1].z += a.y * w.z; acc2[1].w += a.y * w.w;
        acc2[2].x += a.z * w.x; acc2[2].y += a.z * w.y; acc2[2].z += a.z * w.z; acc2[2].w += a.z * w.w;
        acc2[3].x += a.w * w.x; acc2[3].y += a.w * w.y; acc2[3].z += a.w * w.z; acc2[3].w += a.w * w.w;
    }
#pragma unroll
    for (int qq = 0; qq < 4; qq++)
        *(float4*)&Bq[(q0 + qg + qq) * HD + f0] = acc2[qq];
}

// ---------------- fused: edge blocks [0,2048) + ga(layer+1) blocks [2048,2304) ----------------
template <int OUTT, bool FIN, bool GA>
__global__ __launch_bounds__(256, 3) void k_edge_ga(
    const float* __restrict__ Ag, const float* __restrict__ Bq, float* __restrict__ x_q,
    const float* __restrict__ wdrow, const short* __restrict__ wsT,
    const float* __restrict__ b2v, const float* __restrict__ Wc, const float* __restrict__ cbp,
    const int* __restrict__ erow, const float* __restrict__ gridp,
    const float* __restrict__ qp, float* __restrict__ out, float* __restrict__ maggr,
    const float* __restrict__ hg, float* __restrict__ Ag2,
    const float* __restrict__ W1top, const float* __restrict__ b1,
    const float* __restrict__ Wn1top, const float* __restrict__ bn1,
    const float* __restrict__ Wn2g, const float* __restrict__ bn2g,
    int updateH, float* __restrict__ hg_out) {
    __shared__ float S1[HD * 20];
    __shared__ float S2[HD * 20];
    int tid = threadIdx.x;

    if (GA && blockIdx.x >= EBLK) {
        ga_body(S1, S2, (blockIdx.x - EBLK) * 16, tid, hg, Ag2, W1top, b1,
                Wn1top, bn1, Wn2g, bn2g, updateH, hg_out);
        return;
    }

    float* sdist = S1;                 // 128
    float* scm   = S1 + 128;           // 128
    float* sdir  = S1 + 256;           // 384
    float* xs    = S1 + 640;           // 24
    float* scoef = S1 + 704;           // <= 640
    int*   sgi   = (int*)S2;           // 128

    int q0 = blockIdx.x * QB;
    int wid = tid >> 6, lane = tid & 63, quad = lane >> 4, c = lane & 15;

    if (tid < QB * 3) xs[tid] = x_q[q0 * 3 + tid];
    __syncthreads();
    if (tid < EB) {
        int e = tid, q = e >> 4;
        int gi = erow[q0 * DEG + e] - N_PTS;
        sgi[e] = gi;
        int gl = gi & (GPTS - 1);
        float r0 = gridp[gl * 3 + 0] - xs[q * 3 + 0];
        float r1 = gridp[gl * 3 + 1] - xs[q * 3 + 1];
        float r2 = gridp[gl * 3 + 2] - xs[q * 3 + 2];
        float dist = sqrtf(r0 * r0 + r1 * r1 + r2 * r2);
        float inv = 1.0f / (dist + 1e-8f);
        sdist[e] = dist;
        sdir[0 * EB + e] = r0 * inv;
        sdir[1 * EB + e] = r1 * inv;
        sdir[2 * EB + e] = r2 * inv;
        float cw = 0.5f * (__cosf(dist * 0.31415926535897931f) + 1.0f);
        scm[e] = (dist <= 10.0f) ? cw : 0.0f;
    }
    __syncthreads();

    int gi_[2]; float dist_[2];
#pragma unroll
    for (int mi = 0; mi < 2; mi++) {
        int e = (wid * 2 + mi) * 16 + c;
        gi_[mi] = sgi[e];
        dist_[mi] = sdist[e];
    }

    floatx4 acc[2][8];
#pragma unroll
    for (int mi = 0; mi < 2; mi++)
#pragma unroll
        for (int n = 0; n < 8; n++) acc[mi][n] = (floatx4)0.f;

#pragma unroll
    for (int ch = 0; ch < 4; ch++) {
        int kb = ch * 32 + quad * 8;
        float4 wd0 = *(const float4*)(wdrow + kb);
        float4 wd1 = *(const float4*)(wdrow + kb + 4);
        short8 afr[2];
#pragma unroll
        for (int mi = 0; mi < 2; mi++) {
            int q = wid * 2 + mi;
            float dist = dist_[mi];
            const float4* ap = (const float4*)(Ag + gi_[mi] * HD + kb);
            float4 a0 = ap[0], a1 = ap[1];
            const float4* bp4 = (const float4*)(Bq + (q0 + q) * HD + kb);
            float4 b0 = bp4[0], b1 = bp4[1];
            short8 v;
            v[0] = f2bf(silu_f(a0.x + b0.x + dist * wd0.x));
            v[1] = f2bf(silu_f(a0.y + b0.y + dist * wd0.y));
            v[2] = f2bf(silu_f(a0.z + b0.z + dist * wd0.z));
            v[3] = f2bf(silu_f(a0.w + b0.w + dist * wd0.w));
            v[4] = f2bf(silu_f(a1.x + b1.x + dist * wd1.x));
            v[5] = f2bf(silu_f(a1.y + b1.y + dist * wd1.y));
            v[6] = f2bf(silu_f(a1.z + b1.z + dist * wd1.z));
            v[7] = f2bf(silu_f(a1.w + b1.w + dist * wd1.w));
            afr[mi] = v;
        }
#pragma unroll
        for (int n = 0; n < 8; n++) {
            short8 bfr = *(const short8*)(wsT + (n * 16 + c) * HD + kb);
            acc[0][n] = __builtin_amdgcn_mfma_f32_16x16x32_bf16(afr[0], bfr, acc[0][n], 0, 0, 0);
            acc[1][n] = __builtin_amdgcn_mfma_f32_16x16x32_bf16(afr[1], bfr, acc[1][n], 0, 0, 0);
        }
    }

#pragma unroll
    for (int mi = 0; mi < 2; mi++) {
        int q = wid * 2 + mi;
        int ebase = q * 16;
        float cmr[4];
#pragma unroll
        for (int r = 0; r < 4; r++) cmr[r] = scm[ebase + quad * 4 + r];
        float apc[4][OUTT];
#pragma unroll
        for (int r = 0; r < 4; r++)
#pragma unroll
            for (int t = 0; t < OUTT; t++) apc[r][t] = 0.f;
#pragma unroll
        for (int n = 0; n < 8; n++) {
            int f = n * 16 + c;
            float be2v = b2v[f];
            float wcv[OUTT];
            if (FIN) {
#pragma unroll
                for (int t = 0; t < OUTT; t++) wcv[t] = Wc[f * 5 + t];
            } else {
                wcv[0] = Wc[f];
            }
            float cs = 0.f;
#pragma unroll
            for (int r = 0; r < 4; r++) {
                float v = silu_f(acc[mi][n][r] + be2v) * cmr[r];
                cs += v;
#pragma unroll
                for (int t = 0; t < OUTT; t++) apc[r][t] += v * wcv[t];
            }
            cs += __shfl_xor(cs, 16, 64);
            cs += __shfl_xor(cs, 32, 64);
            if (!FIN && lane < 16) maggr[(q0 + q) * HD + f] = cs * 0.0625f;
        }
#pragma unroll
        for (int t = 0; t < OUTT; t++) {
#pragma unroll
            for (int r = 0; r < 4; r++) {
                float v = apc[r][t];
                v += __shfl_xor(v, 1, 64);
                v += __shfl_xor(v, 2, 64);
                v += __shfl_xor(v, 4, 64);
                v += __shfl_xor(v, 8, 64);
                if (c == 0) scoef[(ebase + quad * 4 + r) * OUTT + t] = v;
            }
        }
    }
    __syncthreads();

    if (tid < QB * 3 * OUTT) {
        int qq = tid / (3 * OUTT), rem = tid % (3 * OUTT), t = rem / 3, c2 = rem % 3;
        float cbv = cbp[t];
        float s = 0.f;
#pragma unroll 4
        for (int r = 0; r < 16; r++) {
            int ee = qq * 16 + r;
            s += (scoef[ee * OUTT + t] + cbv) * sdir[c2 * EB + ee];
        }
        float dd = s * 0.0625f;
        if (FIN) out[(q0 + qq) * 15 + t * 3 + c2] = xs[qq * 3 + c2] + dd - qp[(q0 + qq) * 3 + c2];
        else x_q[(q0 + qq) * 3 + c2] = xs[qq * 3 + c2] + dd;
    }
}

extern "C" void kernel_launch(void* const* d_in, const int* in_sizes, int n_in,
                              void* d_out, int out_size, void* d_ws, size_t ws_size,
                              hipStream_t stream) {
    float* out = (float*)d_out;
    int fill_blocks = (out_size + 255) / 256;

    static const int exp_sz[16] = { 49152, 524288, 1536, 131584, 512, 65536, 512, 384,
                                    3, 640, 5, 131072, 512, 65536, 512, 524288 };
    bool ok = (n_in == 16);
    for (int i = 0; ok && i < 16; i++) if (in_sizes[i] != exp_sz[i]) ok = false;
    if (!ok || ws_size < (size_t)40 * 1024 * 1024) {
        k_fillf<<<fill_blocks, 256, 0, stream>>>(out, 777.0f, out_size);
        return;
    }

    const float* qp    = (const float*)d_in[0];
    const float* codes = (const float*)d_in[1];
    const float* gridp = (const float*)d_in[2];
    const float* eW1   = (const float*)d_in[3];
    const float* eb1   = (const float*)d_in[4];
    const float* eW2   = (const float*)d_in[5];
    const float* eb2   = (const float*)d_in[6];
    const float* cW    = (const float*)d_in[7];
    const float* cb    = (const float*)d_in[8];
    const float* fcW   = (const float*)d_in[9];
    const float* fcb   = (const float*)d_in[10];
    const float* nW1   = (const float*)d_in[11];
    const float* nb1   = (const float*)d_in[12];
    const float* nW2   = (const float*)d_in[13];
    const float* nb2   = (const float*)d_in[14];
    const int*   erow  = (const int*)d_in[15];

    float* ws = (float*)d_ws;
    float* x_q  = ws;  ws += N_PTS * 3;
    float* h_q  = ws;  ws += N_PTS * HD;
    float* hg_a = ws;  ws += N_GRID * HD;
    float* hg_b = ws;  ws += N_GRID * HD;
    float* Ag0  = ws;  ws += N_GRID * HD;
    float* Ag1  = ws;  ws += N_GRID * HD;
    float* Bqb  = ws;  ws += N_PTS * HD;
    float* mgb  = ws;  ws += N_PTS * HD;
    short* wsT  = (short*)ws;   // 4 layers x 16384 bf16
    float* Agb[2] = { Ag0, Ag1 };

    k_init<<<2048, 256, 0, stream>>>(qp, codes, x_q, hg_a, h_q, Bqb);
    k_prep<<<(4 * HD * HD + 255) / 256, 256, 0, stream>>>(eW2, wsT);

    // layer-0 ga standalone: A_g(0), h_g(1)
    k_ga<<<GABLK, 256, 0, stream>>>(hg_a, Agb[0], eW1, eb1,
                                    nW1, nb1, nW2, nb2, 1, hg_b);
    float* hg_cur = hg_b;       // h_g for layer 1
    float* hg_next = hg_a;

    for (int i = 0; i < 4; i++) {
        int fin = (i == 3);
        const float* W1l = eW1 + i * 257 * 128;
        if (i > 0) {
            int p = i - 1;
            k_nb<<<N_PTS / 32, 256, 0, stream>>>(h_q, mgb,
                                                 nW1 + p * 256 * 128, nb1 + p * 128,
                                                 nW2 + p * 16384, nb2 + p * 128,
                                                 W1l + 128 * 128, Bqb);
        }
        if (!fin) {
            int L = i + 1;      // ga layer riding along
            const float* W1n = eW1 + L * 257 * 128;
            k_edge_ga<1, false, true><<<EBLK + GABLK, 256, 0, stream>>>(
                Agb[i & 1], Bqb, x_q, W1l + 256 * 128, wsT + i * 16384, eb2 + i * 128,
                cW + i * 128, cb + i, erow, gridp, qp, out, mgb,
                hg_cur, Agb[L & 1], W1n, eb1 + L * 128,
                nW1 + L * 256 * 128, nb1 + L * 128, nW2 + L * 16384, nb2 + L * 128,
                (L < 3) ? 1 : 0, hg_next);
            float* tmp = hg_cur; hg_cur = hg_next; hg_next = tmp;
        } else {
            k_edge_ga<5, true, false><<<EBLK, 256, 0, stream>>>(
                Agb[i & 1], Bqb, x_q, W1l + 256 * 128, wsT + i * 16384, eb2 + i * 128,
                fcW, fcb, erow, gridp, qp, out, mgb,
                nullptr, nullptr, nullptr, nullptr,
                nullptr, nullptr, nullptr, nullptr, 0, nullptr);
        }
    }
}